// Round 8
// baseline (61.941 us; speedup 1.0000x reference)
//
#include <hip/hip_runtime.h>
#include <math.h>

#define NP 16384
#define NG 2048
#define NC 17

#define TSH 3            // tile = 8x8 voxels in (x,y)
#define NTX 25
#define NTY 25
#define NTILE (NTX * NTY)  // 625

#define SEGC 32          // per-wave candidate segment cap (expected mean ~3)
#define SEGP 64          // per-wave point segment cap (expected mean ~6.5)
#define CCAP (4 * SEGC)  // 128 total candidate cap per tile
#define ROWF 40          // floats per staged candidate row

#define GRIDSZ 0.4f
#define PCMINX -40.0f
#define PCMINY -40.0f
#define PCMINZ -1.0f
#define SCALE_MULTC 3.0f

// Row layout (40 floats):
// [0:3] murot, [3:12] rot (row-major), [12:15] 1/scales,
// [15] opa, [16] 1/u, [17] 1/v, [18] v/u, [19] rad (int bitcast),
// [20:37] semantics, [37] vx, [38] vy, [39] vz (int bitcast)
__global__ __launch_bounds__(256)
void fused_kernel(const float* __restrict__ pts,
                  const float* __restrict__ means3D,
                  const float* __restrict__ opas,
                  const float* __restrict__ uu,
                  const float* __restrict__ vv,
                  const float* __restrict__ semantics,
                  const float* __restrict__ scales,
                  const float* __restrict__ rot3D,
                  float* __restrict__ out) {
    __shared__ unsigned short candSeg[4][SEGC];
    __shared__ unsigned short ptSeg[4][SEGP];
    __shared__ int candCnt[4], ptCnt[4];
    __shared__ float rows[CCAP][ROWF];   // 20 KB

    const int tid  = threadIdx.x;
    const int lane = tid & 63;
    const int w    = tid >> 6;
    const int t    = blockIdx.x;
    const int tx   = t % NTX, ty = t / NTX;

    // ---- Phase A: bin primitives (wave w scans g in [w*512, w*512+512)) ----
    unsigned cl = 0;
#pragma unroll 2
    for (int it = 0; it < 8; ++it) {
        int g = w * 512 + it * 64 + lane;
        float mx = means3D[g * 3 + 0], my = means3D[g * 3 + 1];
        float sx = scales[g * 3 + 0], sy = scales[g * 3 + 1], sz = scales[g * 3 + 2];
        int vx = (int)floorf((mx - PCMINX) / GRIDSZ);
        int vy = (int)floorf((my - PCMINY) / GRIDSZ);
        float smax = fmaxf(sx, fmaxf(sy, sz));
        int rad = (int)ceilf(smax * SCALE_MULTC / GRIDSZ);
        if (rad < 1) rad = 1;
        // arithmetic >> floors negatives: tile range covering [vx-rad, vx+rad]
        bool ov = (((vx - rad) >> TSH) <= tx) & (((vx + rad) >> TSH) >= tx) &
                  (((vy - rad) >> TSH) <= ty) & (((vy + rad) >> TSH) >= ty);
        unsigned long long bal = __ballot(ov);
        if (ov) {
            int pos = (int)cl + (int)__popcll(bal & ((1ull << lane) - 1ull));
            if (pos < SEGC) candSeg[w][pos] = (unsigned short)g;
        }
        cl += (unsigned)__popcll(bal);
    }
    if (lane == 0) candCnt[w] = min((int)cl, SEGC);

    __syncthreads();

    const int pc1 = candCnt[0];
    const int pc2 = pc1 + candCnt[1];
    const int pc3 = pc2 + candCnt[2];
    const int totalCand = pc3 + candCnt[3];

    // ---- Phase A2: stage derived rows (one thread per candidate, ascending g) ----
    if (tid < totalCand) {
        int s, idx;
        if (tid < pc1)      { s = 0; idx = tid; }
        else if (tid < pc2) { s = 1; idx = tid - pc1; }
        else if (tid < pc3) { s = 2; idx = tid - pc2; }
        else                { s = 3; idx = tid - pc3; }
        int g = candSeg[s][idx];
        float mx = means3D[g * 3 + 0], my = means3D[g * 3 + 1], mz = means3D[g * 3 + 2];
        float sx = scales[g * 3 + 0], sy = scales[g * 3 + 1], sz = scales[g * 3 + 2];
        float r[9];
#pragma unroll
        for (int i = 0; i < 9; ++i) r[i] = rot3D[g * 9 + i];
        float* R = rows[tid];
        R[0] = mx * r[0] + my * r[3] + mz * r[6];
        R[1] = mx * r[1] + my * r[4] + mz * r[7];
        R[2] = mx * r[2] + my * r[5] + mz * r[8];
#pragma unroll
        for (int i = 0; i < 9; ++i) R[3 + i] = r[i];
        R[12] = 1.0f / sx; R[13] = 1.0f / sy; R[14] = 1.0f / sz;
        R[15] = opas[g];
        float ug = uu[g], vg = vv[g];
        R[16] = 1.0f / ug;
        R[17] = 1.0f / vg;
        R[18] = vg / ug;
        int vx = (int)floorf((mx - PCMINX) / GRIDSZ);
        int vy = (int)floorf((my - PCMINY) / GRIDSZ);
        int vz = (int)floorf((mz - PCMINZ) / GRIDSZ);
        float smax = fmaxf(sx, fmaxf(sy, sz));
        int rad = (int)ceilf(smax * SCALE_MULTC / GRIDSZ);
        if (rad < 1) rad = 1;
        R[19] = __int_as_float(rad);
#pragma unroll
        for (int c = 0; c < NC; ++c) R[20 + c] = semantics[(size_t)g * NC + c];
        R[37] = __int_as_float(vx);
        R[38] = __int_as_float(vy);
        R[39] = __int_as_float(vz);
    }

    // ---- Phase B: bin points (wave w scans p in [w*4096, w*4096+4096)) ----
    unsigned pl = 0;
#pragma unroll 4
    for (int it = 0; it < 64; ++it) {
        int p = w * 4096 + it * 64 + lane;
        float x = pts[p * 3 + 0], y = pts[p * 3 + 1];
        int jx = ((int)floorf((x - PCMINX) / GRIDSZ)) >> TSH;
        int jy = ((int)floorf((y - PCMINY) / GRIDSZ)) >> TSH;
        bool ov = (jx == tx) & (jy == ty);
        unsigned long long bal = __ballot(ov);
        if (ov) {
            int pos = (int)pl + (int)__popcll(bal & ((1ull << lane) - 1ull));
            if (pos < SEGP) ptSeg[w][pos] = (unsigned short)p;
        }
        pl += (unsigned)__popcll(bal);
    }
    if (lane == 0) ptCnt[w] = min((int)pl, SEGP);

    __syncthreads();

    const int qp1 = ptCnt[0];
    const int qp2 = qp1 + ptCnt[1];
    const int qp3 = qp2 + ptCnt[2];
    const int totalPts = qp3 + ptCnt[3];

    // ---- Phase C: wave w evaluates point batch w (totalPts <= 256) ----
    if (w * 64 >= totalPts) return;   // idle waves exit (after last barrier)

    int j = w * 64 + lane;
    bool act = j < totalPts;
    int p = 0;
    float px = 0.0f, py = 0.0f, pz = 0.0f;
    int ix = 0, iy = 0, iz = 0;
    if (act) {
        int s, idx;
        if (j < qp1)      { s = 0; idx = j; }
        else if (j < qp2) { s = 1; idx = j - qp1; }
        else if (j < qp3) { s = 2; idx = j - qp2; }
        else              { s = 3; idx = j - qp3; }
        p = ptSeg[s][idx];
        px = pts[p * 3 + 0]; py = pts[p * 3 + 1]; pz = pts[p * 3 + 2];
        ix = (int)floorf((px - PCMINX) / GRIDSZ);
        iy = (int)floorf((py - PCMINY) / GRIDSZ);
        iz = (int)floorf((pz - PCMINZ) / GRIDSZ);
    }

    float density = 0.0f, logbin = 0.0f;
    float acc[NC];
#pragma unroll
    for (int c = 0; c < NC; ++c) acc[c] = 0.0f;

    // Uniform candidate loop: all operand reads are LDS broadcasts; evaluation
    // is fully predicated (a=0 outside => fma/log contribute nothing).
    for (int k = 0; k < totalCand; ++k) {
        const float* R = rows[k];
        int cvx = __float_as_int(R[37]);
        int cvy = __float_as_int(R[38]);
        int cvz = __float_as_int(R[39]);
        int rad = __float_as_int(R[19]);
        int cheb = max(max(abs(ix - cvx), abs(iy - cvy)), abs(iz - cvz));
        float l0 = px * R[3] + py * R[6] + pz * R[9]  - R[0];
        float l1 = px * R[4] + py * R[7] + pz * R[10] - R[1];
        float l2 = px * R[5] + py * R[8] + pz * R[11] - R[2];
        float t0 = l0 * R[12], t1 = l1 * R[13], t2 = l2 * R[14];
        float s0 = t0 * t0 + 1e-8f;
        float s1 = t1 * t1 + 1e-8f;
        float s2 = t2 * t2 + 1e-8f;
        float f = __powf(__powf(s0, R[17]) + __powf(s1, R[17]), R[18]) +
                  __powf(s2, R[16]);
        float a = R[15] * __expf(-0.5f * f);
        a = (cheb <= rad) ? a : 0.0f;
        density += a;
#pragma unroll
        for (int c = 0; c < NC; ++c) acc[c] = fmaf(a, R[20 + c], acc[c]);
        logbin += __logf(1.0f - fminf(a, 1.0f - 1e-4f));
    }

    if (act) {
        float inv = 1.0f / (density + 1e-9f);
#pragma unroll
        for (int c = 0; c < NC; ++c) out[(size_t)p * NC + c] = acc[c] * inv;
        out[(size_t)NP * NC + p] = 1.0f - expf(logbin);
        out[(size_t)NP * NC + NP + p] = density;
    }
}

extern "C" void kernel_launch(void* const* d_in, const int* in_sizes, int n_in,
                              void* d_out, int out_size, void* d_ws, size_t ws_size,
                              hipStream_t stream) {
    const float* pts       = (const float*)d_in[0];
    const float* means3D   = (const float*)d_in[1];
    const float* opas      = (const float*)d_in[2];
    const float* uu        = (const float*)d_in[3];
    const float* vv        = (const float*)d_in[4];
    const float* semantics = (const float*)d_in[5];
    const float* scales    = (const float*)d_in[6];
    const float* rot3D     = (const float*)d_in[7];
    float* out = (float*)d_out;

    fused_kernel<<<NTILE, 256, 0, stream>>>(pts, means3D, opas, uu, vv, semantics,
                                            scales, rot3D, out);
}